// Round 3
// baseline (84.410 us; speedup 1.0000x reference)
//
#include <hip/hip_runtime.h>
#include <math.h>

#define BB 64
#define NN 2000
#define HH 128
#define NHEAD 8
#define S2 16            // k2 splits per batch
#define S4 32            // k4 splits per batch

// ---------------- K1: glimpse_q and qk[b][h][j] (scale 1/4 folded) ----------------
__global__ __launch_bounds__(128) void k1_prep(
    const float* __restrict__ pe, const float* __restrict__ cls,
    const float* __restrict__ Wqg, const float* __restrict__ Wqf,
    const float* __restrict__ Wql, const float* __restrict__ Wk,
    const int* __restrict__ lp, float* __restrict__ qk_out) {
  __shared__ float4 sc4[32], sl4[32];
  __shared__ float q[HH];
  int b = blockIdx.x, t = threadIdx.x;
  int last = lp[b];
  if (t < 32) {
    sc4[t] = ((const float4*)(cls + b*HH))[t];
    sl4[t] = ((const float4*)(pe + ((long)b*NN + last)*HH))[t];
  }
  __syncthreads();
  const float4* wg = (const float4*)(Wqg + t*HH);
  const float4* wf = (const float4*)(Wqf + t*HH);
  const float4* wl = (const float4*)(Wql + t*HH);
  float acc = 0.f;
  #pragma unroll 8
  for (int j = 0; j < 32; j++) {
    float4 g = wg[j], f = wf[j], l = wl[j], c = sc4[j], s = sl4[j];
    acc += g.x*c.x + g.y*c.y + g.z*c.z + g.w*c.w;
    acc += (f.x+l.x)*s.x + (f.y+l.y)*s.y + (f.z+l.z)*s.z + (f.w+l.w)*s.w;
  }
  q[t] = acc;
  __syncthreads();
  #pragma unroll
  for (int h = 0; h < NHEAD; h++) {
    float a = 0.f;
    #pragma unroll
    for (int d = 0; d < 16; d++)
      a += q[h*16+d] * Wk[(h*16+d)*HH + t];
    qk_out[(b*NHEAD + h)*HH + t] = a * 0.25f;
  }
}

// ---------------- K2: fully register-resident streaming attention ----------------
// grid (S2, B), 256 threads. 16 threads/row, 2 row-streams, qk + wacc in VGPRs.
__global__ __launch_bounds__(256) void k2_attn(
    const float* __restrict__ pe, const float* __restrict__ qk,
    const int* __restrict__ lp, float* __restrict__ lout, float* __restrict__ Wout,
    int rpb) {
  int b = blockIdx.y, sp = blockIdx.x, tid = threadIdx.x;
  int o = tid & 15, rr = tid >> 4;
  int lane = tid & 63, w = tid >> 6;

  // qk fragment in registers: cols {4o..4o+3} (t=0) and {64+4o..} (t=1)
  const float4* qk4 = (const float4*)(qk + b*NHEAD*HH);
  float4 qreg[NHEAD][2];
  #pragma unroll
  for (int h = 0; h < NHEAD; h++) {
    qreg[h][0] = qk4[h*32 + o];
    qreg[h][1] = qk4[h*32 + 16 + o];
  }

  int last = lp[b];
  int r0 = sp * rpb, r1 = min(r0 + rpb, NN);
  const float4* peg = (const float4*)pe;

  float4 wacc[NHEAD][2];
  float lacc[NHEAD];
  #pragma unroll
  for (int h = 0; h < NHEAD; h++) {
    wacc[h][0] = make_float4(0.f,0.f,0.f,0.f);
    wacc[h][1] = make_float4(0.f,0.f,0.f,0.f);
    lacc[h] = 0.f;
  }

  for (int base = r0; base < r1; base += 32) {
    int nA = base + rr, nB = base + 16 + rr;
    bool vA = nA < r1, vB = nB < r1;
    long offA = (long)(b*NN + (vA ? nA : r1-1)) * 32;
    long offB = (long)(b*NN + (vB ? nB : r1-1)) * 32;
    float4 a0 = peg[offA + o],      a1 = peg[offA + 16 + o];
    float4 b0 = peg[offB + o],      b1 = peg[offB + 16 + o];
    float sA[NHEAD], sB[NHEAD];
    #pragma unroll
    for (int h = 0; h < NHEAD; h++) {
      float4 q0 = qreg[h][0], q1 = qreg[h][1];
      sA[h] = a0.x*q0.x + a0.y*q0.y + a0.z*q0.z + a0.w*q0.w
            + a1.x*q1.x + a1.y*q1.y + a1.z*q1.z + a1.w*q1.w;
      sB[h] = b0.x*q0.x + b0.y*q0.y + b0.z*q0.z + b0.w*q0.w
            + b1.x*q1.x + b1.y*q1.y + b1.z*q1.z + b1.w*q1.w;
    }
    #pragma unroll
    for (int h = 0; h < NHEAD; h++) {
      #pragma unroll
      for (int d = 1; d < 16; d <<= 1) {
        sA[h] += __shfl_xor(sA[h], d);
        sB[h] += __shfl_xor(sB[h], d);
      }
    }
    bool mA = vA && (nA != last), mB = vB && (nB != last);
    #pragma unroll
    for (int h = 0; h < NHEAD; h++) {
      float pA = mA ? __expf(sA[h]) : 0.f;
      float pB = mB ? __expf(sB[h]) : 0.f;
      wacc[h][0].x += pA*a0.x + pB*b0.x;
      wacc[h][0].y += pA*a0.y + pB*b0.y;
      wacc[h][0].z += pA*a0.z + pB*b0.z;
      wacc[h][0].w += pA*a0.w + pB*b0.w;
      wacc[h][1].x += pA*a1.x + pB*b1.x;
      wacc[h][1].y += pA*a1.y + pB*b1.y;
      wacc[h][1].z += pA*a1.z + pB*b1.z;
      wacc[h][1].w += pA*a1.w + pB*b1.w;
      lacc[h] += pA + pB;     // each row counted 16x (all o-lanes); fixed in k34
    }
  }

  // cross-slot reduce within wave (lanes o, o+16, o+32, o+48 hold same cols)
  #pragma unroll
  for (int h = 0; h < NHEAD; h++) {
    #pragma unroll
    for (int t = 0; t < 2; t++) {
      #pragma unroll
      for (int d = 16; d < 64; d <<= 1) {
        wacc[h][t].x += __shfl_xor(wacc[h][t].x, d);
        wacc[h][t].y += __shfl_xor(wacc[h][t].y, d);
        wacc[h][t].z += __shfl_xor(wacc[h][t].z, d);
        wacc[h][t].w += __shfl_xor(wacc[h][t].w, d);
      }
    }
    float v = lacc[h];
    #pragma unroll
    for (int d = 1; d < 64; d <<= 1) v += __shfl_xor(v, d);
    lacc[h] = v;
  }

  __shared__ float4 red4[1024];   // [w][o][h][t] -> w*256 + o*16 + h*2 + t
  __shared__ float redl[32];      // [w][h]
  if (lane < 16) {
    #pragma unroll
    for (int h = 0; h < NHEAD; h++) {
      red4[w*256 + lane*16 + h*2 + 0] = wacc[h][0];
      red4[w*256 + lane*16 + h*2 + 1] = wacc[h][1];
    }
  }
  if (lane == 0) {
    #pragma unroll
    for (int h = 0; h < NHEAD; h++) redl[w*NHEAD + h] = lacc[h];
  }
  __syncthreads();
  {
    int o2 = tid >> 4, h2 = (tid >> 1) & 7, t2 = tid & 1;
    float4 s0 = red4[tid], s1 = red4[256 + tid], s2 = red4[512 + tid], s3 = red4[768 + tid];
    float4 s;
    s.x = s0.x + s1.x + s2.x + s3.x;
    s.y = s0.y + s1.y + s2.y + s3.y;
    s.z = s0.z + s1.z + s2.z + s3.z;
    s.w = s0.w + s1.w + s2.w + s3.w;
    float4* Wo = (float4*)(Wout + (long)(b*S2 + sp)*NHEAD*HH);
    Wo[h2*32 + t2*16 + o2] = s;
  }
  if (tid < NHEAD)
    lout[(b*S2 + sp)*NHEAD + tid] = redl[tid] + redl[8+tid] + redl[16+tid] + redl[24+tid];
}

// ---------------- K34: reduce split partials + matvec chain -> lq ----------------
__global__ __launch_bounds__(256) void k34(
    const float* __restrict__ lpart, const float* __restrict__ Wpart,
    const float* __restrict__ Wv, const float* __restrict__ Wc,
    const float* __restrict__ bc, const float* __restrict__ lWk,
    float* __restrict__ lq_out) {
  int b = blockIdx.x, tid = threadIdx.x;
  __shared__ float Wns[NHEAD*HH];
  __shared__ float ls[NHEAD];
  __shared__ float tmp[2][HH];
  __shared__ float outf[HH], fq[HH];
  for (int e = tid; e < NHEAD*HH; e += 256) {
    float a = 0.f;
    #pragma unroll 4
    for (int s = 0; s < S2; s++) a += Wpart[((long)(b*S2+s)*NHEAD)*HH + e];
    Wns[e] = a;
  }
  if (tid < NHEAD) {
    float l = 0.f;
    for (int s = 0; s < S2; s++) l += lpart[(b*S2+s)*NHEAD + tid];
    ls[tid] = l * (1.f/16.f);        // undo 16x over-count from k2
  }
  __syncthreads();
  int t = tid & 127, half = tid >> 7;
  {  // outf = Wv @ Wn[h], h = t>>4, normalized by ls
    int h = t >> 4;
    const float4* wv = (const float4*)(Wv + t*HH);
    const float4* wn = (const float4*)(Wns + h*HH);
    float a = 0.f;
    #pragma unroll 4
    for (int j = half*16; j < half*16 + 16; j++) {
      float4 v = wv[j], n = wn[j];
      a += v.x*n.x + v.y*n.y + v.z*n.z + v.w*n.w;
    }
    tmp[half][t] = a;
    __syncthreads();
    if (half == 0) outf[t] = (tmp[0][t] + tmp[1][t]) / ls[t>>4];
    __syncthreads();
  }
  {  // fq = Wc @ outf + bc
    const float4* wc = (const float4*)(Wc + t*HH);
    const float4* of = (const float4*)outf;
    float a = 0.f;
    #pragma unroll 4
    for (int k = half*16; k < half*16 + 16; k++) {
      float4 v = wc[k], n = of[k];
      a += v.x*n.x + v.y*n.y + v.z*n.z + v.w*n.w;
    }
    tmp[half][t] = a;
    __syncthreads();
    if (half == 0) fq[t] = tmp[0][t] + tmp[1][t] + bc[t];
    __syncthreads();
  }
  {  // lq = (fq @ lWk) / sqrt(128)
    float a = 0.f;
    #pragma unroll 4
    for (int i = half*64; i < half*64 + 64; i++)
      a += fq[i] * lWk[i*HH + t];
    tmp[half][t] = a;
    __syncthreads();
    if (half == 0)
      lq_out[b*HH + t] = (tmp[0][t] + tmp[1][t]) * 0.08838834764831845f;
  }
}

// ---------------- K4: pointer logits -> exp(10*tanh - 10) + partial sums ----------------
__global__ __launch_bounds__(256) void k4_logits(
    const float* __restrict__ pe, const float* __restrict__ lq,
    const int* __restrict__ lp, float* __restrict__ eout, float* __restrict__ psum,
    int rpb4) {
  int b = blockIdx.y, sp = blockIdx.x, tid = threadIdx.x;
  int r = tid >> 3, o = tid & 7;
  // lq fragment in registers
  const float4* lq4 = (const float4*)(lq + b*HH);
  float4 lreg[4];
  #pragma unroll
  for (int t = 0; t < 4; t++) lreg[t] = lq4[o + 8*t];

  __shared__ float red[4];
  int last = lp[b];
  int r0 = sp*rpb4, r1 = min(r0+rpb4, NN);
  const float4* peg = (const float4*)pe;
  float mysum = 0.f;
  for (int base = r0; base < r1; base += 64) {
    int nA = base + r, nB = base + 32 + r;
    bool vA = nA < r1, vB = nB < r1;
    long offA = (long)(b*NN + (vA ? nA : r1-1)) * 32;
    long offB = (long)(b*NN + (vB ? nB : r1-1)) * 32;
    float4 a4[4], b4[4];
    #pragma unroll
    for (int t = 0; t < 4; t++) { a4[t] = peg[offA + o + 8*t]; b4[t] = peg[offB + o + 8*t]; }
    float accA = 0.f, accB = 0.f;
    #pragma unroll
    for (int t = 0; t < 4; t++) {
      float4 k4 = lreg[t];
      accA += a4[t].x*k4.x + a4[t].y*k4.y + a4[t].z*k4.z + a4[t].w*k4.w;
      accB += b4[t].x*k4.x + b4[t].y*k4.y + b4[t].z*k4.z + b4[t].w*k4.w;
    }
    #pragma unroll
    for (int d = 1; d < 8; d <<= 1) {
      accA += __shfl_xor(accA, d);
      accB += __shfl_xor(accB, d);
    }
    if (o == 0) {
      // exp(10*tanh(x)-10) = exp(-20/(exp(2x)+1)), branchless and tanhf-free
      if (vA) {
        float e = (nA == last) ? 0.f : __expf(-20.f / (__expf(2.f*accA) + 1.f));
        eout[b*NN + nA] = e;
        mysum += e;
      }
      if (vB) {
        float e = (nB == last) ? 0.f : __expf(-20.f / (__expf(2.f*accB) + 1.f));
        eout[b*NN + nB] = e;
        mysum += e;
      }
    }
  }
  #pragma unroll
  for (int d = 1; d < 64; d <<= 1) mysum += __shfl_xor(mysum, d);
  int w = tid >> 6;
  if ((tid & 63) == 0) red[w] = mysum;
  __syncthreads();
  if (tid == 0) psum[b*S4 + sp] = red[0] + red[1] + red[2] + red[3];
}

// ---------------- K5: scale ----------------
__global__ __launch_bounds__(256) void k5_scale(
    const float* __restrict__ eout, const float* __restrict__ psum,
    float* __restrict__ out) {
  int b = blockIdx.y, sp = blockIdx.x, tid = threadIdx.x;
  __shared__ float S;
  if (tid == 0) {
    float a = 0.f;
    for (int s = 0; s < S4; s++) a += psum[b*S4 + s];
    S = a;
  }
  __syncthreads();
  float inv = 1.f / S;
  int per = (NN + gridDim.x - 1) / gridDim.x;
  int lo = sp*per, hi = min(lo + per, NN);
  for (int n = lo + tid; n < hi; n += 256)
    out[b*NN + n] = eout[b*NN + n] * inv;
}

extern "C" void kernel_launch(void* const* d_in, const int* in_sizes, int n_in,
                              void* d_out, int out_size, void* d_ws, size_t ws_size,
                              hipStream_t stream) {
  (void)in_sizes; (void)n_in; (void)out_size; (void)ws_size;
  const float* pe   = (const float*)d_in[0];
  const float* cls  = (const float*)d_in[1];
  const float* Wqg  = (const float*)d_in[2];
  const float* Wqf  = (const float*)d_in[3];
  const float* Wql  = (const float*)d_in[4];
  const float* Wk   = (const float*)d_in[5];
  const float* Wv   = (const float*)d_in[6];
  const float* lWk  = (const float*)d_in[7];
  const float* Wc   = (const float*)d_in[8];
  const float* bc   = (const float*)d_in[9];
  const int*   lp   = (const int*)d_in[10];
  float* out = (float*)d_out;
  float* ws  = (float*)d_ws;

  const int rpb  = (NN + S2 - 1) / S2;   // 125
  const int rpb4 = (NN + S4 - 1) / S4;   // 63

  float* qk    = ws;                               // 64*8*128
  float* lpart = qk + BB*NHEAD*HH;                 // 64*16*8
  float* Wpart = lpart + BB*S2*NHEAD;              // 64*16*8*128
  float* lq    = Wpart + (size_t)BB*S2*NHEAD*HH;   // 64*128
  float* eout  = lq + BB*HH;                       // 64*2000
  float* psum  = eout + BB*NN;                     // 64*32

  k1_prep<<<dim3(BB), dim3(128), 0, stream>>>(pe, cls, Wqg, Wqf, Wql, Wk, lp, qk);
  k2_attn<<<dim3(S2, BB), dim3(256), 0, stream>>>(pe, qk, lp, lpart, Wpart, rpb);
  k34<<<dim3(BB), dim3(256), 0, stream>>>(lpart, Wpart, Wv, Wc, bc, lWk, lq);
  k4_logits<<<dim3(S4, BB), dim3(256), 0, stream>>>(pe, lq, lp, eout, psum, rpb4);
  k5_scale<<<dim3(8, BB), dim3(256), 0, stream>>>(eout, psum, out);
}

// Round 4
// 76.048 us; speedup vs baseline: 1.1100x; 1.1100x over previous
//
#include <hip/hip_runtime.h>
#include <math.h>

#define BB 64
#define NN 2000
#define HH 128
#define NHEAD 8
#define SP 8            // splits per batch for k2a/k2b/k4

// ---------------- K1: glimpse_q and qk[b][h][j] (scale 1/4 folded) ----------------
__global__ __launch_bounds__(128) void k1_prep(
    const float* __restrict__ pe, const float* __restrict__ cls,
    const float* __restrict__ Wqg, const float* __restrict__ Wqf,
    const float* __restrict__ Wql, const float* __restrict__ Wk,
    const int* __restrict__ lp, float* __restrict__ qk_out) {
  __shared__ float4 sc4[32], sl4[32];
  __shared__ float q[HH];
  int b = blockIdx.x, t = threadIdx.x;
  int last = lp[b];
  if (t < 32) {
    sc4[t] = ((const float4*)(cls + b*HH))[t];
    sl4[t] = ((const float4*)(pe + ((long)b*NN + last)*HH))[t];
  }
  __syncthreads();
  const float4* wg = (const float4*)(Wqg + t*HH);
  const float4* wf = (const float4*)(Wqf + t*HH);
  const float4* wl = (const float4*)(Wql + t*HH);
  float acc = 0.f;
  #pragma unroll 8
  for (int j = 0; j < 32; j++) {
    float4 g = wg[j], f = wf[j], l = wl[j], c = sc4[j], s = sl4[j];
    acc += g.x*c.x + g.y*c.y + g.z*c.z + g.w*c.w;
    acc += (f.x+l.x)*s.x + (f.y+l.y)*s.y + (f.z+l.z)*s.z + (f.w+l.w)*s.w;
  }
  q[t] = acc;
  __syncthreads();
  #pragma unroll
  for (int h = 0; h < NHEAD; h++) {
    float a = 0.f;
    #pragma unroll
    for (int d = 0; d < 16; d++)
      a += q[h*16+d] * Wk[(h*16+d)*HH + t];
    qk_out[(b*NHEAD + h)*HH + t] = a * 0.25f;
  }
}

// ---------------- K2a: scores, thread-owns-row, qk via scalar loads ----------------
__global__ __launch_bounds__(256) void k2a_scores(
    const float* __restrict__ pe, const float* __restrict__ qk,
    const int* __restrict__ lp, float* __restrict__ pout) {
  int b = blockIdx.y, sp = blockIdx.x, tid = threadIdx.x;
  int n = sp*256 + tid;
  int nc = min(n, NN-1);
  const float4* prow = (const float4*)(pe + ((long)b*NN + nc)*HH);
  const float4* qk4  = (const float4*)(qk + (long)b*NHEAD*HH);   // block-uniform -> s_load
  float d[NHEAD];
  #pragma unroll
  for (int h = 0; h < NHEAD; h++) d[h] = 0.f;
  #pragma unroll 2
  for (int j = 0; j < 32; j += 4) {
    float4 v0 = prow[j], v1 = prow[j+1], v2 = prow[j+2], v3 = prow[j+3];
    #pragma unroll
    for (int h = 0; h < NHEAD; h++) {
      float4 q0 = qk4[h*32+j], q1 = qk4[h*32+j+1];
      float4 q2 = qk4[h*32+j+2], q3 = qk4[h*32+j+3];
      d[h] += v0.x*q0.x + v0.y*q0.y + v0.z*q0.z + v0.w*q0.w
            + v1.x*q1.x + v1.y*q1.y + v1.z*q1.z + v1.w*q1.w
            + v2.x*q2.x + v2.y*q2.y + v2.z*q2.z + v2.w*q2.w
            + v3.x*q3.x + v3.y*q3.y + v3.z*q3.z + v3.w*q3.w;
    }
  }
  int last = lp[b];
  bool live = (n < NN) && (n != last);
  float4 p0, p1;
  p0.x = live ? __expf(d[0]) : 0.f;
  p0.y = live ? __expf(d[1]) : 0.f;
  p0.z = live ? __expf(d[2]) : 0.f;
  p0.w = live ? __expf(d[3]) : 0.f;
  p1.x = live ? __expf(d[4]) : 0.f;
  p1.y = live ? __expf(d[5]) : 0.f;
  p1.z = live ? __expf(d[6]) : 0.f;
  p1.w = live ? __expf(d[7]) : 0.f;
  if (n < NN) {
    float4* po = (float4*)(pout + ((long)b*NN + n)*NHEAD);
    po[0] = p0; po[1] = p1;
  }
}

// ---------------- K2b: W[b,sp,h,:] = sum_n p[h][n]*pe[n][:], exact l-sums ----------------
__global__ __launch_bounds__(256) void k2b_wsum(
    const float* __restrict__ pe, const float* __restrict__ pin,
    float* __restrict__ Wpart, float* __restrict__ lpart) {
  int b = blockIdx.y, sp = blockIdx.x, tid = threadIdx.x;
  int w = tid >> 6, lane = tid & 63;
  __shared__ float4 pst[4][128];          // per-wave p chunk [64 n][8 h]
  __shared__ float4 wred[NHEAD][4][32];   // [h][wave][j4]
  __shared__ float lred[4][NHEAD];
  int chunk = sp*256 + w*64;
  const float4* pin4 = (const float4*)pin;
  {
    float4 z = make_float4(0.f,0.f,0.f,0.f);
    int k0 = lane, k1 = lane + 64;
    int n0 = chunk + (k0 >> 1), n1 = chunk + (k1 >> 1);
    pst[w][k0] = (n0 < NN) ? pin4[((long)b*NN + n0)*2 + (k0&1)] : z;
    pst[w][k1] = (n1 < NN) ? pin4[((long)b*NN + n1)*2 + (k1&1)] : z;
  }
  __syncthreads();
  int rhalf = lane >> 5, j4 = lane & 31;
  const float4* peg = (const float4*)pe;
  float4 wa[NHEAD];
  float la[NHEAD];
  #pragma unroll
  for (int h = 0; h < NHEAD; h++) { wa[h] = make_float4(0.f,0.f,0.f,0.f); la[h] = 0.f; }
  for (int i = 0; i < 32; i++) {
    int nl = i*2 + rhalf;
    int ng = chunk + nl;
    float4 v = peg[((long)b*NN + min(ng, NN-1))*32 + j4];
    float4 pa = pst[w][nl*2], pb = pst[w][nl*2+1];
    wa[0].x += pa.x*v.x; wa[0].y += pa.x*v.y; wa[0].z += pa.x*v.z; wa[0].w += pa.x*v.w; la[0] += pa.x;
    wa[1].x += pa.y*v.x; wa[1].y += pa.y*v.y; wa[1].z += pa.y*v.z; wa[1].w += pa.y*v.w; la[1] += pa.y;
    wa[2].x += pa.z*v.x; wa[2].y += pa.z*v.y; wa[2].z += pa.z*v.z; wa[2].w += pa.z*v.w; la[2] += pa.z;
    wa[3].x += pa.w*v.x; wa[3].y += pa.w*v.y; wa[3].z += pa.w*v.z; wa[3].w += pa.w*v.w; la[3] += pa.w;
    wa[4].x += pb.x*v.x; wa[4].y += pb.x*v.y; wa[4].z += pb.x*v.z; wa[4].w += pb.x*v.w; la[4] += pb.x;
    wa[5].x += pb.y*v.x; wa[5].y += pb.y*v.y; wa[5].z += pb.y*v.z; wa[5].w += pb.y*v.w; la[5] += pb.y;
    wa[6].x += pb.z*v.x; wa[6].y += pb.z*v.y; wa[6].z += pb.z*v.z; wa[6].w += pb.z*v.w; la[6] += pb.z;
    wa[7].x += pb.w*v.x; wa[7].y += pb.w*v.y; wa[7].z += pb.w*v.z; wa[7].w += pb.w*v.w; la[7] += pb.w;
  }
  // combine row-halves (lane ^ 32)
  #pragma unroll
  for (int h = 0; h < NHEAD; h++) {
    wa[h].x += __shfl_xor(wa[h].x, 32);
    wa[h].y += __shfl_xor(wa[h].y, 32);
    wa[h].z += __shfl_xor(wa[h].z, 32);
    wa[h].w += __shfl_xor(wa[h].w, 32);
    la[h]   += __shfl_xor(la[h], 32);
  }
  if (lane < 32) {
    #pragma unroll
    for (int h = 0; h < NHEAD; h++) wred[h][w][lane] = wa[h];
  }
  if (lane == 0) {
    #pragma unroll
    for (int h = 0; h < NHEAD; h++) lred[w][h] = la[h];
  }
  __syncthreads();
  int h2 = tid >> 5, c = tid & 31;
  float4 s0 = wred[h2][0][c], s1 = wred[h2][1][c], s2 = wred[h2][2][c], s3 = wred[h2][3][c];
  float4 s;
  s.x = s0.x + s1.x + s2.x + s3.x;
  s.y = s0.y + s1.y + s2.y + s3.y;
  s.z = s0.z + s1.z + s2.z + s3.z;
  s.w = s0.w + s1.w + s2.w + s3.w;
  ((float4*)(Wpart + ((long)(b*SP + sp)*NHEAD + h2)*HH))[c] = s;
  if (tid < NHEAD)
    lpart[(b*SP + sp)*NHEAD + tid] =
        lred[0][tid] + lred[1][tid] + lred[2][tid] + lred[3][tid];
}

// ---------------- K34: reduce split partials + matvec chain -> lq ----------------
__global__ __launch_bounds__(256) void k34(
    const float* __restrict__ lpart, const float* __restrict__ Wpart,
    const float* __restrict__ Wv, const float* __restrict__ Wc,
    const float* __restrict__ bc, const float* __restrict__ lWk,
    float* __restrict__ lq_out) {
  int b = blockIdx.x, tid = threadIdx.x;
  __shared__ float Wns[NHEAD*HH];
  __shared__ float ls[NHEAD];
  __shared__ float tmp[2][HH];
  __shared__ float outf[HH], fq[HH];
  for (int e = tid; e < NHEAD*HH; e += 256) {
    float a = 0.f;
    #pragma unroll
    for (int s = 0; s < SP; s++) a += Wpart[((long)(b*SP+s)*NHEAD)*HH + e];
    Wns[e] = a;
  }
  if (tid < NHEAD) {
    float l = 0.f;
    #pragma unroll
    for (int s = 0; s < SP; s++) l += lpart[(b*SP+s)*NHEAD + tid];
    ls[tid] = l;                      // exact now (no overcount)
  }
  __syncthreads();
  int t = tid & 127, half = tid >> 7;
  {
    int h = t >> 4;
    const float4* wv = (const float4*)(Wv + t*HH);
    const float4* wn = (const float4*)(Wns + h*HH);
    float a = 0.f;
    #pragma unroll 4
    for (int j = half*16; j < half*16 + 16; j++) {
      float4 v = wv[j], nn = wn[j];
      a += v.x*nn.x + v.y*nn.y + v.z*nn.z + v.w*nn.w;
    }
    tmp[half][t] = a;
    __syncthreads();
    if (half == 0) outf[t] = (tmp[0][t] + tmp[1][t]) / ls[t>>4];
    __syncthreads();
  }
  {
    const float4* wc = (const float4*)(Wc + t*HH);
    const float4* of = (const float4*)outf;
    float a = 0.f;
    #pragma unroll 4
    for (int k = half*16; k < half*16 + 16; k++) {
      float4 v = wc[k], nn = of[k];
      a += v.x*nn.x + v.y*nn.y + v.z*nn.z + v.w*nn.w;
    }
    tmp[half][t] = a;
    __syncthreads();
    if (half == 0) fq[t] = tmp[0][t] + tmp[1][t] + bc[t];
    __syncthreads();
  }
  {
    float a = 0.f;
    #pragma unroll 4
    for (int i = half*64; i < half*64 + 64; i++)
      a += fq[i] * lWk[i*HH + t];
    tmp[half][t] = a;
    __syncthreads();
    if (half == 0)
      lq_out[b*HH + t] = (tmp[0][t] + tmp[1][t]) * 0.08838834764831845f;
  }
}

// ---------------- K4: pointer logits, thread-owns-row, lq via scalar loads ----------------
__global__ __launch_bounds__(256) void k4_logits(
    const float* __restrict__ pe, const float* __restrict__ lq,
    const int* __restrict__ lp, float* __restrict__ eout, float* __restrict__ psum) {
  int b = blockIdx.y, sp = blockIdx.x, tid = threadIdx.x;
  int n = sp*256 + tid;
  int nc = min(n, NN-1);
  const float4* prow = (const float4*)(pe + ((long)b*NN + nc)*HH);
  const float4* lq4  = (const float4*)(lq + (long)b*HH);   // block-uniform -> s_load
  float a0 = 0.f, a1 = 0.f, a2 = 0.f, a3 = 0.f;
  #pragma unroll 2
  for (int j = 0; j < 32; j += 4) {
    float4 v0 = prow[j], v1 = prow[j+1], v2 = prow[j+2], v3 = prow[j+3];
    float4 q0 = lq4[j], q1 = lq4[j+1], q2 = lq4[j+2], q3 = lq4[j+3];
    a0 += v0.x*q0.x + v0.y*q0.y + v0.z*q0.z + v0.w*q0.w;
    a1 += v1.x*q1.x + v1.y*q1.y + v1.z*q1.z + v1.w*q1.w;
    a2 += v2.x*q2.x + v2.y*q2.y + v2.z*q2.z + v2.w*q2.w;
    a3 += v3.x*q3.x + v3.y*q3.y + v3.z*q3.z + v3.w*q3.w;
  }
  float acc = (a0 + a1) + (a2 + a3);
  int last = lp[b];
  // exp(10*tanh(x)-10) = exp(-20/(exp(2x)+1))
  float e = (n < NN && n != last) ? __expf(-20.f / (__expf(2.f*acc) + 1.f)) : 0.f;
  if (n < NN) eout[b*NN + n] = e;
  float s = e;
  #pragma unroll
  for (int d = 1; d < 64; d <<= 1) s += __shfl_xor(s, d);
  __shared__ float red[4];
  if ((tid & 63) == 0) red[tid >> 6] = s;
  __syncthreads();
  if (tid == 0) psum[b*SP + sp] = red[0] + red[1] + red[2] + red[3];
}

// ---------------- K5: scale ----------------
__global__ __launch_bounds__(256) void k5_scale(
    const float* __restrict__ eout, const float* __restrict__ psum,
    float* __restrict__ out) {
  int b = blockIdx.y, sp = blockIdx.x, tid = threadIdx.x;
  __shared__ float S;
  if (tid == 0) {
    float a = 0.f;
    #pragma unroll
    for (int s = 0; s < SP; s++) a += psum[b*SP + s];
    S = a;
  }
  __syncthreads();
  float inv = 1.f / S;
  int lo = sp*250;
  int n = lo + tid;
  if (tid < 250) out[b*NN + n] = eout[b*NN + n] * inv;
}

extern "C" void kernel_launch(void* const* d_in, const int* in_sizes, int n_in,
                              void* d_out, int out_size, void* d_ws, size_t ws_size,
                              hipStream_t stream) {
  (void)in_sizes; (void)n_in; (void)out_size; (void)ws_size;
  const float* pe   = (const float*)d_in[0];
  const float* cls  = (const float*)d_in[1];
  const float* Wqg  = (const float*)d_in[2];
  const float* Wqf  = (const float*)d_in[3];
  const float* Wql  = (const float*)d_in[4];
  const float* Wk   = (const float*)d_in[5];
  const float* Wv   = (const float*)d_in[6];
  const float* lWk  = (const float*)d_in[7];
  const float* Wc   = (const float*)d_in[8];
  const float* bc   = (const float*)d_in[9];
  const int*   lp   = (const int*)d_in[10];
  float* out = (float*)d_out;
  float* ws  = (float*)d_ws;

  float* qk    = ws;                                   // 64*8*128      = 65536
  float* p     = qk + BB*NHEAD*HH;                     // 64*2000*8     = 1024000
  float* lpart = p + (size_t)BB*NN*NHEAD;              // 64*8*8        = 4096
  float* Wpart = lpart + BB*SP*NHEAD;                  // 64*8*8*128    = 524288
  float* lq    = Wpart + (size_t)BB*SP*NHEAD*HH;       // 64*128        = 8192
  float* eout  = lq + BB*HH;                           // 64*2000       = 128000
  float* psum  = eout + BB*NN;                         // 64*8          = 512

  k1_prep<<<dim3(BB), dim3(128), 0, stream>>>(pe, cls, Wqg, Wqf, Wql, Wk, lp, qk);
  k2a_scores<<<dim3(SP, BB), dim3(256), 0, stream>>>(pe, qk, lp, p);
  k2b_wsum<<<dim3(SP, BB), dim3(256), 0, stream>>>(pe, p, Wpart, lpart);
  k34<<<dim3(BB), dim3(256), 0, stream>>>(lpart, Wpart, Wv, Wc, bc, lWk, lq);
  k4_logits<<<dim3(SP, BB), dim3(256), 0, stream>>>(pe, lq, lp, eout, psum);
  k5_scale<<<dim3(SP, BB), dim3(256), 0, stream>>>(eout, psum, out);
}

// Round 6
// 73.007 us; speedup vs baseline: 1.1562x; 1.0416x over previous
//
#include <hip/hip_runtime.h>
#include <hip/hip_cooperative_groups.h>
#include <math.h>

namespace cg = cooperative_groups;

#define BB 64
#define NN 2000
#define HH 128
#define NHEAD 8
#define SP 8
#define RPB 250     // rows per block (SP*RPB == NN)

// ---- shared-memory arena offsets (phase-disjoint aliasing) ----
// phase 1-2:  pl[250][8] @0 (8000) | wred[8][4][32]f4 @8000 (16384) | lred @24384 (128)
// phase 0:    sc4 @0 (512) | sl4 @512 (512) | qv @1024 (512)
// k34 stage:  Wns @0 (4096) | lsm @4096 (32) | tmp @4128 (1024) | outf @5152 | fq @5664
// phase 3:    red @24512 (16)
#define SM_BYTES 24528

// =========================== device bodies (shared by both paths) ===========================

__device__ __forceinline__ void body_qk(
    const float* pe, const float* cls, const float* Wqg, const float* Wqf,
    const float* Wql, const float* Wk, int b, int last, int tid,
    float4* sc4, float4* sl4, float* qv, float* qk) {
  if (tid < 32) {
    sc4[tid] = ((const float4*)(cls + b*HH))[tid];
    sl4[tid] = ((const float4*)(pe + ((long)b*NN + last)*HH))[tid];
  }
  __syncthreads();
  if (tid < 128) {
    const float4* wg = (const float4*)(Wqg + tid*HH);
    const float4* wf = (const float4*)(Wqf + tid*HH);
    const float4* wl = (const float4*)(Wql + tid*HH);
    float acc = 0.f;
    #pragma unroll 8
    for (int j = 0; j < 32; j++) {
      float4 g = wg[j], f = wf[j], l = wl[j], c = sc4[j], s = sl4[j];
      acc += g.x*c.x + g.y*c.y + g.z*c.z + g.w*c.w;
      acc += (f.x+l.x)*s.x + (f.y+l.y)*s.y + (f.z+l.z)*s.z + (f.w+l.w)*s.w;
    }
    qv[tid] = acc;
  }
  __syncthreads();
  if (tid < 128) {
    #pragma unroll
    for (int h = 0; h < NHEAD; h++) {
      float a = 0.f;
      #pragma unroll
      for (int d = 0; d < 16; d++)
        a += qv[h*16+d] * Wk[(h*16+d)*HH + tid];
      qk[(b*NHEAD + h)*HH + tid] = a * 0.25f;   // fold 1/sqrt(head_dim)
    }
  }
}

// scores for 250 rows -> pl (LDS), then W/l partial sums -> Wpart/lpart
__device__ __forceinline__ void body_scores_wsum(
    const float* pe, const float* qk, int b, int sp, int last, int tid,
    float (*pl)[NHEAD], float4 (*wred)[4][32], float (*lred)[NHEAD],
    float* Wpart, float* lpart) {
  const int n0 = sp * RPB;
  if (tid < RPB) {
    const int n = n0 + tid;
    const float4* prow = (const float4*)(pe + ((long)b*NN + n)*HH);
    const float4* qk4  = (const float4*)(qk + (long)b*NHEAD*HH);   // uniform -> s_load
    float d[NHEAD];
    #pragma unroll
    for (int h = 0; h < NHEAD; h++) d[h] = 0.f;
    #pragma unroll 2
    for (int j = 0; j < 32; j += 4) {
      float4 v0 = prow[j], v1 = prow[j+1], v2 = prow[j+2], v3 = prow[j+3];
      #pragma unroll
      for (int h = 0; h < NHEAD; h++) {
        float4 q0 = qk4[h*32+j],   q1 = qk4[h*32+j+1];
        float4 q2 = qk4[h*32+j+2], q3 = qk4[h*32+j+3];
        d[h] += v0.x*q0.x + v0.y*q0.y + v0.z*q0.z + v0.w*q0.w
              + v1.x*q1.x + v1.y*q1.y + v1.z*q1.z + v1.w*q1.w
              + v2.x*q2.x + v2.y*q2.y + v2.z*q2.z + v2.w*q2.w
              + v3.x*q3.x + v3.y*q3.y + v3.z*q3.z + v3.w*q3.w;
      }
    }
    const bool live = (n != last);
    float4 p0, p1;
    p0.x = live ? __expf(d[0]) : 0.f;  p0.y = live ? __expf(d[1]) : 0.f;
    p0.z = live ? __expf(d[2]) : 0.f;  p0.w = live ? __expf(d[3]) : 0.f;
    p1.x = live ? __expf(d[4]) : 0.f;  p1.y = live ? __expf(d[5]) : 0.f;
    p1.z = live ? __expf(d[6]) : 0.f;  p1.w = live ? __expf(d[7]) : 0.f;
    ((float4*)pl[tid])[0] = p0;
    ((float4*)pl[tid])[1] = p1;
  }
  __syncthreads();

  const int w = tid >> 6, lane = tid & 63;
  const int st = w*2 + (lane >> 5);       // row-stream 0..7
  const int j4 = lane & 31;
  const float4* peg = (const float4*)(pe + ((long)b*NN + n0)*HH);
  float4 wa[NHEAD];
  float  la[NHEAD];
  #pragma unroll
  for (int h = 0; h < NHEAD; h++) { wa[h] = make_float4(0.f,0.f,0.f,0.f); la[h] = 0.f; }
  #pragma unroll 4
  for (int i = 0; i < 32; i++) {
    const int nl = st + (i << 3);
    if (nl < RPB) {
      float4 v  = peg[nl*32 + j4];
      float4 pa = *(const float4*)&pl[nl][0];
      float4 pb = *(const float4*)&pl[nl][4];
      wa[0].x += pa.x*v.x; wa[0].y += pa.x*v.y; wa[0].z += pa.x*v.z; wa[0].w += pa.x*v.w; la[0] += pa.x;
      wa[1].x += pa.y*v.x; wa[1].y += pa.y*v.y; wa[1].z += pa.y*v.z; wa[1].w += pa.y*v.w; la[1] += pa.y;
      wa[2].x += pa.z*v.x; wa[2].y += pa.z*v.y; wa[2].z += pa.z*v.z; wa[2].w += pa.z*v.w; la[2] += pa.z;
      wa[3].x += pa.w*v.x; wa[3].y += pa.w*v.y; wa[3].z += pa.w*v.z; wa[3].w += pa.w*v.w; la[3] += pa.w;
      wa[4].x += pb.x*v.x; wa[4].y += pb.x*v.y; wa[4].z += pb.x*v.z; wa[4].w += pb.x*v.w; la[4] += pb.x;
      wa[5].x += pb.y*v.x; wa[5].y += pb.y*v.y; wa[5].z += pb.y*v.z; wa[5].w += pb.y*v.w; la[5] += pb.y;
      wa[6].x += pb.z*v.x; wa[6].y += pb.z*v.y; wa[6].z += pb.z*v.z; wa[6].w += pb.z*v.w; la[6] += pb.z;
      wa[7].x += pb.w*v.x; wa[7].y += pb.w*v.y; wa[7].z += pb.w*v.z; wa[7].w += pb.w*v.w; la[7] += pb.w;
    }
  }
  #pragma unroll
  for (int h = 0; h < NHEAD; h++) {
    wa[h].x += __shfl_xor(wa[h].x, 32);
    wa[h].y += __shfl_xor(wa[h].y, 32);
    wa[h].z += __shfl_xor(wa[h].z, 32);
    wa[h].w += __shfl_xor(wa[h].w, 32);
    la[h]   += __shfl_xor(la[h], 32);
  }
  if (lane < 32) {
    #pragma unroll
    for (int h = 0; h < NHEAD; h++) wred[h][w][lane] = wa[h];
  }
  if (lane == 0) {
    #pragma unroll
    for (int h = 0; h < NHEAD; h++) lred[w][h] = la[h];
  }
  __syncthreads();
  const int h2 = tid >> 5, c = tid & 31;
  float4 s0 = wred[h2][0][c], s1 = wred[h2][1][c], s2 = wred[h2][2][c], s3 = wred[h2][3][c];
  float4 s;
  s.x = s0.x + s1.x + s2.x + s3.x;
  s.y = s0.y + s1.y + s2.y + s3.y;
  s.z = s0.z + s1.z + s2.z + s3.z;
  s.w = s0.w + s1.w + s2.w + s3.w;
  ((float4*)(Wpart + ((long)(b*SP + sp)*NHEAD + h2)*HH))[c] = s;
  if (tid < NHEAD)
    lpart[(b*SP + sp)*NHEAD + tid] =
        lred[0][tid] + lred[1][tid] + lred[2][tid] + lred[3][tid];
}

__device__ __forceinline__ void body_k34(
    const float* lpart, const float* Wpart, const float* Wv, const float* Wc,
    const float* bc, const float* lWk, int B2, int tid,
    float* Wns, float* lsm, float (*tmp)[HH], float* outf, float* fq,
    float* lq) {
  for (int e = tid; e < NHEAD*HH; e += 256) {
    float a = 0.f;
    #pragma unroll
    for (int s = 0; s < SP; s++) a += Wpart[((long)(B2*SP+s)*NHEAD)*HH + e];
    Wns[e] = a;
  }
  if (tid < NHEAD) {
    float l = 0.f;
    #pragma unroll
    for (int s = 0; s < SP; s++) l += lpart[(B2*SP+s)*NHEAD + tid];
    lsm[tid] = l;
  }
  __syncthreads();
  const int t = tid & 127, half = tid >> 7;
  {
    const int h = t >> 4;
    const float4* wv = (const float4*)(Wv + t*HH);
    const float4* wn = (const float4*)(Wns + h*HH);
    float a = 0.f;
    #pragma unroll 4
    for (int j = half*16; j < half*16 + 16; j++) {
      float4 v = wv[j], nn = wn[j];
      a += v.x*nn.x + v.y*nn.y + v.z*nn.z + v.w*nn.w;
    }
    tmp[half][t] = a;
    __syncthreads();
    if (half == 0) outf[t] = (tmp[0][t] + tmp[1][t]) / lsm[t>>4];
    __syncthreads();
  }
  {
    const float4* wc = (const float4*)(Wc + t*HH);
    const float4* of = (const float4*)outf;
    float a = 0.f;
    #pragma unroll 4
    for (int k = half*16; k < half*16 + 16; k++) {
      float4 v = wc[k], nn = of[k];
      a += v.x*nn.x + v.y*nn.y + v.z*nn.z + v.w*nn.w;
    }
    tmp[half][t] = a;
    __syncthreads();
    if (half == 0) fq[t] = tmp[0][t] + tmp[1][t] + bc[t];
    __syncthreads();
  }
  {
    float a = 0.f;
    #pragma unroll 4
    for (int i = half*64; i < half*64 + 64; i++)
      a += fq[i] * lWk[i*HH + t];
    tmp[half][t] = a;
    __syncthreads();
    if (half == 0)
      lq[B2*HH + t] = (tmp[0][t] + tmp[1][t]) * 0.08838834764831845f;
  }
}

__device__ __forceinline__ float body_logit(
    const float* pe, const float* lq, int b, int n, int last) {
  const float4* prow = (const float4*)(pe + ((long)b*NN + n)*HH);
  const float4* lq4  = (const float4*)(lq + (long)b*HH);   // uniform -> s_load
  float a0 = 0.f, a1 = 0.f, a2 = 0.f, a3 = 0.f;
  #pragma unroll 2
  for (int j = 0; j < 32; j += 4) {
    float4 v0 = prow[j], v1 = prow[j+1], v2 = prow[j+2], v3 = prow[j+3];
    float4 q0 = lq4[j], q1 = lq4[j+1], q2 = lq4[j+2], q3 = lq4[j+3];
    a0 += v0.x*q0.x + v0.y*q0.y + v0.z*q0.z + v0.w*q0.w;
    a1 += v1.x*q1.x + v1.y*q1.y + v1.z*q1.z + v1.w*q1.w;
    a2 += v2.x*q2.x + v2.y*q2.y + v2.z*q2.z + v2.w*q2.w;
    a3 += v3.x*q3.x + v3.y*q3.y + v3.z*q3.z + v3.w*q3.w;
  }
  const float acc = (a0 + a1) + (a2 + a3);
  // exp(10*tanh(x)-10) = exp(-20/(exp(2x)+1))
  return (n != last) ? __expf(-20.f / (__expf(2.f*acc) + 1.f)) : 0.f;
}

// =========================== cooperative mega-kernel ===========================

__global__ __launch_bounds__(256, 2) void mega(
    const float* __restrict__ pe, const float* __restrict__ cls,
    const float* __restrict__ Wqg, const float* __restrict__ Wqf,
    const float* __restrict__ Wql, const float* __restrict__ Wk,
    const float* __restrict__ Wv, const float* __restrict__ lWk,
    const float* __restrict__ Wc, const float* __restrict__ bc,
    const int* __restrict__ lp, float* __restrict__ out,
    float* __restrict__ qk, float* __restrict__ Wpart,
    float* __restrict__ lpart, float* __restrict__ lq,
    float* __restrict__ psum) {
  cg::grid_group grid = cg::this_grid();
  const int gb = blockIdx.x;
  const int b = gb >> 3, sp = gb & 7;
  const int tid = threadIdx.x;

  __shared__ __align__(16) char smraw[SM_BYTES];
  float  (*pl)[NHEAD]      = reinterpret_cast<float(*)[NHEAD]>(smraw);
  float4 (*wred)[4][32]    = reinterpret_cast<float4(*)[4][32]>(smraw + 8000);
  float  (*lred)[NHEAD]    = reinterpret_cast<float(*)[NHEAD]>(smraw + 24384);
  float4 *sc4              = reinterpret_cast<float4*>(smraw);
  float4 *sl4              = reinterpret_cast<float4*>(smraw + 512);
  float  *qv               = reinterpret_cast<float*>(smraw + 1024);
  float  *Wns              = reinterpret_cast<float*>(smraw);
  float  *lsm              = reinterpret_cast<float*>(smraw + 4096);
  float  (*tmp)[HH]        = reinterpret_cast<float(*)[HH]>(smraw + 4128);
  float  *outf             = reinterpret_cast<float*>(smraw + 5152);
  float  *fq               = reinterpret_cast<float*>(smraw + 5664);
  float  *red              = reinterpret_cast<float*>(smraw + 24512);

  const int last = lp[b];

  // phase 0: qk (sp==0 blocks only)
  if (sp == 0)
    body_qk(pe, cls, Wqg, Wqf, Wql, Wk, b, last, tid, sc4, sl4, qv, qk);
  grid.sync();

  // phase 1+2: scores -> pl, weighted sums -> Wpart/lpart
  body_scores_wsum(pe, qk, b, sp, last, tid, pl, wred, lred, Wpart, lpart);
  grid.sync();

  // k34 stage: blocks gb<64 compute lq[gb]
  if (gb < BB)
    body_k34(lpart, Wpart, Wv, Wc, bc, lWk, gb, tid, Wns, lsm, tmp, outf, fq, lq);
  grid.sync();

  // phase 3: logits + per-block partial sum
  const int n3 = sp*RPB + tid;
  float e = (tid < RPB) ? body_logit(pe, lq, b, n3, last) : 0.f;
  {
    float s = e;
    #pragma unroll
    for (int d = 1; d < 64; d <<= 1) s += __shfl_xor(s, d);
    if ((tid & 63) == 0) red[tid >> 6] = s;
    __syncthreads();
    if (tid == 0) psum[b*SP + sp] = red[0] + red[1] + red[2] + red[3];
  }
  grid.sync();

  if (tid < RPB) {
    float S = 0.f;
    #pragma unroll
    for (int s = 0; s < SP; s++) S += psum[b*SP + s];
    out[b*NN + n3] = e / S;
  }
}

// =========================== fallback kernels ===========================

__global__ __launch_bounds__(256) void fb_k1(
    const float* __restrict__ pe, const float* __restrict__ cls,
    const float* __restrict__ Wqg, const float* __restrict__ Wqf,
    const float* __restrict__ Wql, const float* __restrict__ Wk,
    const int* __restrict__ lp, float* __restrict__ qk) {
  __shared__ float4 sc4[32], sl4[32];
  __shared__ float qv[HH];
  int b = blockIdx.x;
  body_qk(pe, cls, Wqg, Wqf, Wql, Wk, b, lp[b], threadIdx.x, sc4, sl4, qv, qk);
}

__global__ __launch_bounds__(256) void fb_kb(
    const float* __restrict__ pe, const float* __restrict__ qk,
    const int* __restrict__ lp, float* __restrict__ Wpart,
    float* __restrict__ lpart) {
  __shared__ float  pl[RPB][NHEAD];
  __shared__ float4 wred[NHEAD][4][32];
  __shared__ float  lred[4][NHEAD];
  int b = blockIdx.y, sp = blockIdx.x;
  body_scores_wsum(pe, qk, b, sp, lp[b], threadIdx.x, pl, wred, lred, Wpart, lpart);
}

__global__ __launch_bounds__(256) void fb_k34(
    const float* __restrict__ lpart, const float* __restrict__ Wpart,
    const float* __restrict__ Wv, const float* __restrict__ Wc,
    const float* __restrict__ bc, const float* __restrict__ lWk,
    float* __restrict__ lq) {
  __shared__ float Wns[NHEAD*HH];
  __shared__ float lsm[NHEAD];
  __shared__ float tmp[2][HH];
  __shared__ float outf[HH], fq[HH];
  body_k34(lpart, Wpart, Wv, Wc, bc, lWk, blockIdx.x, threadIdx.x,
           Wns, lsm, tmp, outf, fq, lq);
}

__global__ __launch_bounds__(256) void fb_kd(
    const float* __restrict__ pe, const float* __restrict__ lq,
    const int* __restrict__ lp, float* __restrict__ eout,
    float* __restrict__ psum) {
  __shared__ float red[4];
  int b = blockIdx.y, sp = blockIdx.x, tid = threadIdx.x;
  int n = sp*RPB + tid;
  float e = (tid < RPB) ? body_logit(pe, lq, b, n, lp[b]) : 0.f;
  if (tid < RPB) eout[b*NN + n] = e;
  float s = e;
  #pragma unroll
  for (int d = 1; d < 64; d <<= 1) s += __shfl_xor(s, d);
  if ((tid & 63) == 0) red[tid >> 6] = s;
  __syncthreads();
  if (tid == 0) psum[b*SP + sp] = red[0] + red[1] + red[2] + red[3];
}

__global__ __launch_bounds__(256) void fb_ke(
    const float* __restrict__ eout, const float* __restrict__ psum,
    float* __restrict__ out) {
  int b = blockIdx.y, sp = blockIdx.x, tid = threadIdx.x;
  __shared__ float S;
  if (tid == 0) {
    float a = 0.f;
    #pragma unroll
    for (int s = 0; s < SP; s++) a += psum[b*SP + s];
    S = a;
  }
  __syncthreads();
  int n = sp*RPB + tid;
  if (tid < RPB) out[b*NN + n] = eout[b*NN + n] / S;
}

// =========================== host launch ===========================

extern "C" void kernel_launch(void* const* d_in, const int* in_sizes, int n_in,
                              void* d_out, int out_size, void* d_ws, size_t ws_size,
                              hipStream_t stream) {
  (void)in_sizes; (void)n_in; (void)out_size; (void)ws_size;
  const float* pe   = (const float*)d_in[0];
  const float* cls  = (const float*)d_in[1];
  const float* Wqg  = (const float*)d_in[2];
  const float* Wqf  = (const float*)d_in[3];
  const float* Wql  = (const float*)d_in[4];
  const float* Wk   = (const float*)d_in[5];
  const float* Wv   = (const float*)d_in[6];
  const float* lWk  = (const float*)d_in[7];
  const float* Wc   = (const float*)d_in[8];
  const float* bc   = (const float*)d_in[9];
  const int*   lp   = (const int*)d_in[10];
  float* out = (float*)d_out;
  float* ws  = (float*)d_ws;

  float* qk    = ws;                                 // 64*8*128
  float* Wpart = qk + BB*NHEAD*HH;                   // 64*8*8*128
  float* lpart = Wpart + (size_t)BB*SP*NHEAD*HH;     // 64*8*8
  float* lq    = lpart + BB*SP*NHEAD;                // 64*128
  float* psum  = lq + BB*HH;                         // 64*8
  float* eout  = psum + BB*SP;                       // 64*2000 (fallback only)

  // capture-safe host-side capability checks (deterministic per device)
  bool coop_ok = false;
  {
    int dev = 0;
    if (hipGetDevice(&dev) == hipSuccess) {
      int attr = 0, ncu = 0, nb = 0;
      hipDeviceGetAttribute(&attr, hipDeviceAttributeCooperativeLaunch, dev);
      hipDeviceGetAttribute(&ncu, hipDeviceAttributeMultiprocessorCount, dev);
      hipError_t oe = hipOccupancyMaxActiveBlocksPerMultiprocessor(
          &nb, (const void*)mega, 256, 0);
      if (attr && oe == hipSuccess && (long)nb * ncu >= (long)BB*SP)
        coop_ok = true;
    }
  }

  if (coop_ok) {
    void* args[] = {
      (void*)&pe, (void*)&cls, (void*)&Wqg, (void*)&Wqf, (void*)&Wql,
      (void*)&Wk, (void*)&Wv, (void*)&lWk, (void*)&Wc, (void*)&bc,
      (void*)&lp, (void*)&out, (void*)&qk, (void*)&Wpart, (void*)&lpart,
      (void*)&lq, (void*)&psum
    };
    hipError_t le = hipLaunchCooperativeKernel((const void*)mega, dim3(BB*SP),
                                               dim3(256), args, 0, stream);
    if (le == hipSuccess) return;
    // launch rejected cleanly -> fall through to multi-kernel path
  }

  fb_k1<<<dim3(BB), dim3(256), 0, stream>>>(pe, cls, Wqg, Wqf, Wql, Wk, lp, qk);
  fb_kb<<<dim3(SP, BB), dim3(256), 0, stream>>>(pe, qk, lp, Wpart, lpart);
  fb_k34<<<dim3(BB), dim3(256), 0, stream>>>(lpart, Wpart, Wv, Wc, bc, lWk, lq);
  fb_kd<<<dim3(SP, BB), dim3(256), 0, stream>>>(pe, lq, lp, eout, psum);
  fb_ke<<<dim3(SP, BB), dim3(256), 0, stream>>>(eout, psum, out);
}